// Round 3
// baseline (793.724 us; speedup 1.0000x reference)
//
#include <hip/hip_runtime.h>
#include <math.h>

#define T_DIM 2048
#define B_DIM 16
#define H_DIM 512
// out: results [T,B,2H] (33,554,432 f32) then attn [B,T,T] (67,108,864 f32)
// ws layout (ushort elements):
//   Xh [B][T][H] @ 0            (16,777,216)
//   Xl           @ 16,777,216
//   Qh           @ 33,554,432
//   Ql           @ 50,331,648
//   Wth [n][k]   @ 67,108,864   (262,144)
//   Wtl          @ 67,371,008   -> total 135,266,304 bytes

typedef short bf16x8 __attribute__((ext_vector_type(8)));
typedef float f32x4 __attribute__((ext_vector_type(4)));

__device__ __forceinline__ unsigned short f2bf(float x) {
    unsigned int u = __float_as_uint(x);
    u += 0x7FFFu + ((u >> 16) & 1u);
    return (unsigned short)(u >> 16);
}
__device__ __forceinline__ float bf2f(unsigned short h) {
    return __uint_as_float(((unsigned int)h) << 16);
}

__device__ __forceinline__ void split8(const float* xs, uint4* ho, uint4* lo) {
    unsigned int hw[4], lw[4];
#pragma unroll
    for (int e = 0; e < 4; ++e) {
        unsigned short h0 = f2bf(xs[2 * e]), h1 = f2bf(xs[2 * e + 1]);
        unsigned short l0 = f2bf(xs[2 * e] - bf2f(h0));
        unsigned short l1 = f2bf(xs[2 * e + 1] - bf2f(h1));
        hw[e] = (unsigned int)h0 | ((unsigned int)h1 << 16);
        lw[e] = (unsigned int)l0 | ((unsigned int)l1 << 16);
    }
    *ho = make_uint4(hw[0], hw[1], hw[2], hw[3]);
    *lo = make_uint4(lw[0], lw[1], lw[2], lw[3]);
}

// ---------- Kernel 1: results copy + X split to bf16 hi/lo (batch-major) ----------
__global__ __launch_bounds__(256) void k_prep(const float* __restrict__ X,
                                              const float* __restrict__ RC,
                                              float* __restrict__ out,
                                              unsigned short* __restrict__ Xh,
                                              unsigned short* __restrict__ Xl) {
    int i = blockIdx.x * 256 + threadIdx.x;   // T*B*64 threads, 8 elems each
    int row = i >> 6;                          // t*B + b
    int h0 = (i & 63) * 8;
    int t = row >> 4;
    int b = row & 15;
    const float* xp = X + (size_t)row * H_DIM + h0;
    float4 v0 = *(const float4*)xp;
    float4 v1 = *(const float4*)(xp + 4);
    float* op = out + (size_t)row * (2 * H_DIM) + h0;
    *(float4*)op = v0;
    *(float4*)(op + 4) = v1;
    const float* cp = RC + (size_t)row * H_DIM + h0;
    float4 c0 = *(const float4*)cp;
    float4 c1 = *(const float4*)(cp + 4);
    if (t < 2) { c0 = v0; c1 = v1; }
    *(float4*)(op + H_DIM) = c0;
    *(float4*)(op + H_DIM + 4) = c1;
    float xs[8] = {v0.x, v0.y, v0.z, v0.w, v1.x, v1.y, v1.z, v1.w};
    uint4 ho, lo;
    split8(xs, &ho, &lo);
    size_t dst = ((size_t)b * T_DIM + t) * H_DIM + h0;
    *(uint4*)(Xh + dst) = ho;
    *(uint4*)(Xl + dst) = lo;
}

// ---------- Kernel 2: W -> transposed split Wth/Wtl [n][k] ----------
__global__ __launch_bounds__(256) void k_split_w(const float* __restrict__ W,
                                                 unsigned short* __restrict__ Wth,
                                                 unsigned short* __restrict__ Wtl) {
    int i = blockIdx.x * 256 + threadIdx.x;   // 512*64 threads
    int n = i & 511;
    int k0 = (i >> 9) * 8;
    float xs[8];
#pragma unroll
    for (int j = 0; j < 8; ++j) xs[j] = W[(size_t)(k0 + j) * H_DIM + n];
    uint4 ho, lo;
    split8(xs, &ho, &lo);
    size_t dst = (size_t)n * H_DIM + k0;
    *(uint4*)(Wth + dst) = ho;
    *(uint4*)(Wtl + dst) = lo;
}

// ---------- async staging: one 128x32 bf16 tile per wave, 8 x 1KB chunks ----------
__device__ __forceinline__ void stage_tile(const unsigned short* __restrict__ src,
                                           unsigned short* lds_base,
                                           size_t row_base, int k0, int lane) {
#pragma unroll
    for (int c = 0; c < 8; ++c) {
        const int g = c >> 1, r0 = (c & 1) * 64;
        const unsigned short* gp = src + (row_base + r0 + lane) * H_DIM + k0 + g * 8;
        __builtin_amdgcn_global_load_lds((__attribute__((address_space(1))) void*)gp,
                                         (__attribute__((address_space(3))) void*)(lds_base + (g * 128 + r0) * 8),
                                         16, 0, 0);
    }
}

// ---------- Kernel 3: Q = X @ W via 3-term bf16 MFMA, split epilogue ----------
__global__ __launch_bounds__(256) void k_qgemm_mfma(const unsigned short* __restrict__ Xh,
                                                    const unsigned short* __restrict__ Xl,
                                                    const unsigned short* __restrict__ Wth,
                                                    const unsigned short* __restrict__ Wtl,
                                                    unsigned short* __restrict__ Qh,
                                                    unsigned short* __restrict__ Ql) {
    __shared__ __align__(16) unsigned short Ah[4][128][8], Al[4][128][8], Bh[4][128][8], Bl[4][128][8];
    const int m0 = blockIdx.x * 128;          // rows in [B*T]
    const int n0 = blockIdx.y * 128;          // cols in [H]
    const int tid = threadIdx.x, lane = tid & 63, w = tid >> 6;
    const int t_off = (w >> 1) * 64, s_off = (w & 1) * 64;
    const int l15 = lane & 15, lg = lane >> 4;
    f32x4 acc[4][4] = {};

    for (int k0 = 0; k0 < H_DIM; k0 += 32) {
        if (k0) __syncthreads();
        if      (w == 0) stage_tile(Xh,  &Ah[0][0][0], (size_t)m0, k0, lane);
        else if (w == 1) stage_tile(Xl,  &Al[0][0][0], (size_t)m0, k0, lane);
        else if (w == 2) stage_tile(Wth, &Bh[0][0][0], (size_t)n0, k0, lane);
        else             stage_tile(Wtl, &Bl[0][0][0], (size_t)n0, k0, lane);
        __syncthreads();

        bf16x8 ah[4], al[4], bh[4], bl[4];
#pragma unroll
        for (int i2 = 0; i2 < 4; ++i2) {
            ah[i2] = *(const bf16x8*)&Ah[lg][t_off + i2 * 16 + l15][0];
            al[i2] = *(const bf16x8*)&Al[lg][t_off + i2 * 16 + l15][0];
        }
#pragma unroll
        for (int j = 0; j < 4; ++j) {
            bh[j] = *(const bf16x8*)&Bh[lg][s_off + j * 16 + l15][0];
            bl[j] = *(const bf16x8*)&Bl[lg][s_off + j * 16 + l15][0];
        }
#pragma unroll
        for (int i2 = 0; i2 < 4; ++i2)
#pragma unroll
            for (int j = 0; j < 4; ++j) {
                acc[i2][j] = __builtin_amdgcn_mfma_f32_16x16x32_bf16(ah[i2], bh[j], acc[i2][j], 0, 0, 0);
                acc[i2][j] = __builtin_amdgcn_mfma_f32_16x16x32_bf16(al[i2], bh[j], acc[i2][j], 0, 0, 0);
                acc[i2][j] = __builtin_amdgcn_mfma_f32_16x16x32_bf16(ah[i2], bl[j], acc[i2][j], 0, 0, 0);
            }
    }

#pragma unroll
    for (int i2 = 0; i2 < 4; ++i2)
#pragma unroll
        for (int j = 0; j < 4; ++j)
#pragma unroll
            for (int r = 0; r < 4; ++r) {
                int row = m0 + t_off + i2 * 16 + lg * 4 + r;
                int col = n0 + s_off + j * 16 + l15;
                float q = acc[i2][j][r];
                unsigned short qh = f2bf(q);
                unsigned short ql = f2bf(q - bf2f(qh));
                Qh[(size_t)row * H_DIM + col] = qh;
                Ql[(size_t)row * H_DIM + col] = ql;
            }
}

// ---------- Kernel 4: scores via 3-term bf16 MFMA, async-staged ----------
__global__ __launch_bounds__(256) void k_scores_mfma(const unsigned short* __restrict__ Qh,
                                                     const unsigned short* __restrict__ Ql,
                                                     const unsigned short* __restrict__ Xh,
                                                     const unsigned short* __restrict__ Xl,
                                                     float* __restrict__ attn) {
    const int t0 = blockIdx.x * 128;
    const int s0 = blockIdx.y * 128;
    if (s0 > t0) return;                      // never read by softmax
    const int b = blockIdx.z;
    __shared__ __align__(16) unsigned short Ah[4][128][8], Al[4][128][8], Bh[4][128][8], Bl[4][128][8];
    const int tid = threadIdx.x, lane = tid & 63, w = tid >> 6;
    const int t_off = (w >> 1) * 64, s_off = (w & 1) * 64;
    const int l15 = lane & 15, lg = lane >> 4;
    const size_t rowA = (size_t)b * T_DIM + t0;
    const size_t rowB = (size_t)b * T_DIM + s0;
    f32x4 acc[4][4] = {};

    for (int k0 = 0; k0 < H_DIM; k0 += 32) {
        if (k0) __syncthreads();
        if      (w == 0) stage_tile(Qh, &Ah[0][0][0], rowA, k0, lane);
        else if (w == 1) stage_tile(Ql, &Al[0][0][0], rowA, k0, lane);
        else if (w == 2) stage_tile(Xh, &Bh[0][0][0], rowB, k0, lane);
        else             stage_tile(Xl, &Bl[0][0][0], rowB, k0, lane);
        __syncthreads();

        bf16x8 ah[4], al[4], bh[4], bl[4];
#pragma unroll
        for (int i2 = 0; i2 < 4; ++i2) {
            ah[i2] = *(const bf16x8*)&Ah[lg][t_off + i2 * 16 + l15][0];
            al[i2] = *(const bf16x8*)&Al[lg][t_off + i2 * 16 + l15][0];
        }
#pragma unroll
        for (int j = 0; j < 4; ++j) {
            bh[j] = *(const bf16x8*)&Bh[lg][s_off + j * 16 + l15][0];
            bl[j] = *(const bf16x8*)&Bl[lg][s_off + j * 16 + l15][0];
        }
#pragma unroll
        for (int i2 = 0; i2 < 4; ++i2)
#pragma unroll
            for (int j = 0; j < 4; ++j) {
                acc[i2][j] = __builtin_amdgcn_mfma_f32_16x16x32_bf16(ah[i2], bh[j], acc[i2][j], 0, 0, 0);
                acc[i2][j] = __builtin_amdgcn_mfma_f32_16x16x32_bf16(al[i2], bh[j], acc[i2][j], 0, 0, 0);
                acc[i2][j] = __builtin_amdgcn_mfma_f32_16x16x32_bf16(ah[i2], bl[j], acc[i2][j], 0, 0, 0);
            }
    }

    float* base = attn + (size_t)b * T_DIM * T_DIM;
#pragma unroll
    for (int i2 = 0; i2 < 4; ++i2)
#pragma unroll
        for (int j = 0; j < 4; ++j)
#pragma unroll
            for (int r = 0; r < 4; ++r) {
                int t = t0 + t_off + i2 * 16 + lg * 4 + r;
                int s = s0 + s_off + j * 16 + l15;
                base[(size_t)t * T_DIM + s] = acc[i2][j][r];
            }
}

// ---------- Kernel 5: in-place masked softmax per (b,t) row ----------
__global__ __launch_bounds__(256) void k_softmax(float* __restrict__ attn) {
    const int row = blockIdx.x;
    const int t = row & (T_DIM - 1);
    float* p = attn + (size_t)row * T_DIM;
    const int tid = threadIdx.x;
    const int n = (t >= 2) ? t : 0;
    __shared__ float red[4];

    if (n == 0) {
        const float4 z = {0.f, 0.f, 0.f, 0.f};
        for (int s = tid * 4; s < T_DIM; s += 1024) *(float4*)&p[s] = z;
        return;
    }

    float m = -INFINITY;
    for (int s = tid; s < n; s += 256) m = fmaxf(m, p[s]);
#pragma unroll
    for (int off = 32; off >= 1; off >>= 1) m = fmaxf(m, __shfl_xor(m, off));
    if ((tid & 63) == 0) red[tid >> 6] = m;
    __syncthreads();
    m = fmaxf(fmaxf(red[0], red[1]), fmaxf(red[2], red[3]));
    __syncthreads();

    float sum = 0.f;
    for (int s = tid; s < n; s += 256) sum += expf(p[s] - m);
#pragma unroll
    for (int off = 32; off >= 1; off >>= 1) sum += __shfl_xor(sum, off);
    if ((tid & 63) == 0) red[tid >> 6] = sum;
    __syncthreads();
    sum = red[0] + red[1] + red[2] + red[3];
    const float inv = 1.f / sum;

    for (int s = tid * 4; s < T_DIM; s += 1024) {
        float4 o = {0.f, 0.f, 0.f, 0.f};
        if (s + 3 < n) {
            float4 v = *(float4*)&p[s];
            o.x = expf(v.x - m) * inv;
            o.y = expf(v.y - m) * inv;
            o.z = expf(v.z - m) * inv;
            o.w = expf(v.w - m) * inv;
        } else if (s < n) {
            float tmp[4] = {0.f, 0.f, 0.f, 0.f};
            for (int j = 0; j < 4; ++j)
                if (s + j < n) tmp[j] = expf(p[s + j] - m) * inv;
            o.x = tmp[0]; o.y = tmp[1]; o.z = tmp[2]; o.w = tmp[3];
        }
        *(float4*)&p[s] = o;
    }
}

extern "C" void kernel_launch(void* const* d_in, const int* in_sizes, int n_in,
                              void* d_out, int out_size, void* d_ws, size_t ws_size,
                              hipStream_t stream) {
    const float* inputs   = (const float*)d_in[0];   // [T,B,H]
    const float* rand_ctx = (const float*)d_in[1];   // [T,B,H]
    const float* W        = (const float*)d_in[2];   // [H,H]
    float* out  = (float*)d_out;
    float* attn = out + (size_t)T_DIM * B_DIM * 2 * H_DIM;

    unsigned short* Xh  = (unsigned short*)d_ws;
    unsigned short* Xl  = Xh + (size_t)16777216;
    unsigned short* Qh  = Xh + (size_t)33554432;
    unsigned short* Ql  = Xh + (size_t)50331648;
    unsigned short* Wth = Xh + (size_t)67108864;
    unsigned short* Wtl = Wth + (size_t)262144;

    k_prep<<<dim3(T_DIM * B_DIM * 64 / 256), dim3(256), 0, stream>>>(
        inputs, rand_ctx, out, Xh, Xl);

    k_split_w<<<dim3(128), dim3(256), 0, stream>>>(W, Wth, Wtl);

    k_qgemm_mfma<<<dim3(T_DIM * B_DIM / 128, H_DIM / 128), dim3(256), 0, stream>>>(
        Xh, Xl, Wth, Wtl, Qh, Ql);

    k_scores_mfma<<<dim3(T_DIM / 128, T_DIM / 128, B_DIM), dim3(256), 0, stream>>>(
        Qh, Ql, Xh, Xl, attn);

    k_softmax<<<dim3(B_DIM * T_DIM), dim3(256), 0, stream>>>(attn);
}

// Round 6
// 470.942 us; speedup vs baseline: 1.6854x; 1.6854x over previous
//
#include <hip/hip_runtime.h>
#include <math.h>

#define T_DIM 2048
#define B_DIM 16
#define H_DIM 512
#define NKB   (H_DIM / 32)   // 16 k-blocks of 32
// out: results [T,B,2H] (33,554,432 f32) then attn [B,T,T] (67,108,864 f32)
// ws (ushort), all X/Q arrays stored TILED: tile(rowblk,kblk) = 8KB laid out as
// [g(4)][row(128)][8] — byte-identical to the LDS image, so staging is a linear copy.
//   Xh @0 (16Mi), Xl @16Mi, Qh @32Mi, Ql @48Mi, Wth @64Mi (256Ki), Wtl after.

typedef short bf16x8 __attribute__((ext_vector_type(8)));
typedef float f32x4 __attribute__((ext_vector_type(4)));

__device__ __forceinline__ unsigned short f2bf(float x) {
    unsigned int u = __float_as_uint(x);
    u += 0x7FFFu + ((u >> 16) & 1u);
    return (unsigned short)(u >> 16);
}
__device__ __forceinline__ float bf2f(unsigned short h) {
    return __uint_as_float(((unsigned int)h) << 16);
}
__device__ __forceinline__ size_t tile_off(int rowblk, int kblk) {
    return ((size_t)rowblk * NKB + kblk) * 4096;   // 4096 ushorts = 8KB per tile
}
// element (row r within rowblk-space, col c in [0,H)) inside tiled array:
__device__ __forceinline__ size_t tiled_idx(int r, int c) {
    return tile_off(r >> 7, c >> 5) + (size_t)((c >> 3) & 3) * 1024 + (size_t)(r & 127) * 8 + (c & 7);
}

__device__ __forceinline__ void split8(const float* xs, uint4* ho, uint4* lo) {
    unsigned int hw[4], lw[4];
#pragma unroll
    for (int e = 0; e < 4; ++e) {
        unsigned short h0 = f2bf(xs[2 * e]), h1 = f2bf(xs[2 * e + 1]);
        unsigned short l0 = f2bf(xs[2 * e] - bf2f(h0));
        unsigned short l1 = f2bf(xs[2 * e + 1] - bf2f(h1));
        hw[e] = (unsigned int)h0 | ((unsigned int)h1 << 16);
        lw[e] = (unsigned int)l0 | ((unsigned int)l1 << 16);
    }
    *ho = make_uint4(hw[0], hw[1], hw[2], hw[3]);
    *lo = make_uint4(lw[0], lw[1], lw[2], lw[3]);
}

// ---------- Kernel 1: results copy + X split to bf16 hi/lo (tiled, batch-major) ----------
__global__ __launch_bounds__(256) void k_prep(const float* __restrict__ X,
                                              const float* __restrict__ RC,
                                              float* __restrict__ out,
                                              unsigned short* __restrict__ Xh,
                                              unsigned short* __restrict__ Xl) {
    int i = blockIdx.x * 256 + threadIdx.x;
    int row = i >> 6;                 // t*B + b
    int h0 = (i & 63) * 8;
    int t = row >> 4;
    int b = row & 15;
    const float* xp = X + (size_t)row * H_DIM + h0;
    float4 v0 = *(const float4*)xp;
    float4 v1 = *(const float4*)(xp + 4);
    float* op = out + (size_t)row * (2 * H_DIM) + h0;
    *(float4*)op = v0;
    *(float4*)(op + 4) = v1;
    const float* cp = RC + (size_t)row * H_DIM + h0;
    float4 c0 = *(const float4*)cp;
    float4 c1 = *(const float4*)(cp + 4);
    if (t < 2) { c0 = v0; c1 = v1; }
    *(float4*)(op + H_DIM) = c0;
    *(float4*)(op + H_DIM + 4) = c1;
    float xs[8] = {v0.x, v0.y, v0.z, v0.w, v1.x, v1.y, v1.z, v1.w};
    uint4 ho, lo;
    split8(xs, &ho, &lo);
    int r = b * T_DIM + t;            // batch-major row index
    size_t dst = tiled_idx(r, h0);    // h0 ≡ 0 mod 8 -> 16B aligned
    *(uint4*)(Xh + dst) = ho;
    *(uint4*)(Xl + dst) = lo;
}

// ---------- Kernel 2: W -> transposed split, tiled [n][k] ----------
__global__ __launch_bounds__(256) void k_split_w(const float* __restrict__ W,
                                                 unsigned short* __restrict__ Wth,
                                                 unsigned short* __restrict__ Wtl) {
    int i = blockIdx.x * 256 + threadIdx.x;
    int n = i & 511;
    int k0 = (i >> 9) * 8;
    float xs[8];
#pragma unroll
    for (int j = 0; j < 8; ++j) xs[j] = W[(size_t)(k0 + j) * H_DIM + n];
    uint4 ho, lo;
    split8(xs, &ho, &lo);
    size_t dst = tiled_idx(n, k0);
    *(uint4*)(Wth + dst) = ho;
    *(uint4*)(Wtl + dst) = lo;
}

// ---------- staging: one pre-tiled 8KB tile -> LDS, linear copy, fully coalesced.
// LDS image identical to R3's proven [g][128][8]; lane offset only in the GLOBAL addr.
__device__ __forceinline__ void stage_tile(const unsigned short* __restrict__ src_tile,
                                           unsigned short* lds_base, int lane) {
#pragma unroll
    for (int c = 0; c < 8; ++c) {
        __builtin_amdgcn_global_load_lds(
            (const __attribute__((address_space(1))) void*)(src_tile + c * 512 + lane * 8),
            (__attribute__((address_space(3))) void*)(lds_base + c * 512),
            16, 0, 0);
    }
}

// ---------- Kernel 3: Q = X @ W via 3-term bf16 MFMA (R3 control flow) ----------
__global__ __launch_bounds__(256) void k_qgemm_mfma(const unsigned short* __restrict__ Xh,
                                                    const unsigned short* __restrict__ Xl,
                                                    const unsigned short* __restrict__ Wth,
                                                    const unsigned short* __restrict__ Wtl,
                                                    unsigned short* __restrict__ Qh,
                                                    unsigned short* __restrict__ Ql) {
    __shared__ __align__(16) unsigned short Ah[4][128][8], Al[4][128][8], Bh[4][128][8], Bl[4][128][8];
    const int m0 = blockIdx.x * 128;          // rows in [B*T] batch-major
    const int n0 = blockIdx.y * 128;          // cols in [H]
    const int mblk = m0 >> 7, nblk = n0 >> 7;
    const int tid = threadIdx.x, lane = tid & 63, w = tid >> 6;
    const int t_off = (w >> 1) * 64, s_off = (w & 1) * 64;
    const int l15 = lane & 15, lg = lane >> 4;
    f32x4 acc[4][4] = {};

    for (int ks = 0; ks < NKB; ++ks) {
        if (ks) __syncthreads();
        if      (w == 0) stage_tile(Xh  + tile_off(mblk, ks), &Ah[0][0][0], lane);
        else if (w == 1) stage_tile(Xl  + tile_off(mblk, ks), &Al[0][0][0], lane);
        else if (w == 2) stage_tile(Wth + tile_off(nblk, ks), &Bh[0][0][0], lane);
        else             stage_tile(Wtl + tile_off(nblk, ks), &Bl[0][0][0], lane);
        __syncthreads();

        bf16x8 ah[4], al[4], bh[4], bl[4];
#pragma unroll
        for (int i2 = 0; i2 < 4; ++i2) {
            ah[i2] = *(const bf16x8*)&Ah[lg][t_off + i2 * 16 + l15][0];
            al[i2] = *(const bf16x8*)&Al[lg][t_off + i2 * 16 + l15][0];
        }
#pragma unroll
        for (int j = 0; j < 4; ++j) {
            bh[j] = *(const bf16x8*)&Bh[lg][s_off + j * 16 + l15][0];
            bl[j] = *(const bf16x8*)&Bl[lg][s_off + j * 16 + l15][0];
        }
#pragma unroll
        for (int i2 = 0; i2 < 4; ++i2)
#pragma unroll
            for (int j = 0; j < 4; ++j) {
                acc[i2][j] = __builtin_amdgcn_mfma_f32_16x16x32_bf16(ah[i2], bh[j], acc[i2][j], 0, 0, 0);
                acc[i2][j] = __builtin_amdgcn_mfma_f32_16x16x32_bf16(al[i2], bh[j], acc[i2][j], 0, 0, 0);
                acc[i2][j] = __builtin_amdgcn_mfma_f32_16x16x32_bf16(ah[i2], bl[j], acc[i2][j], 0, 0, 0);
            }
    }

    // scatter epilogue (R3-proven pattern), destination now tiled
#pragma unroll
    for (int i2 = 0; i2 < 4; ++i2)
#pragma unroll
        for (int j = 0; j < 4; ++j)
#pragma unroll
            for (int r = 0; r < 4; ++r) {
                int R = m0 + t_off + i2 * 16 + lg * 4 + r;
                int C = n0 + s_off + j * 16 + l15;
                float q = acc[i2][j][r];
                unsigned short qh = f2bf(q);
                unsigned short ql = f2bf(q - bf2f(qh));
                size_t dst = tiled_idx(R, C);
                Qh[dst] = qh;
                Ql[dst] = ql;
            }
}

// ---------- Kernel 4: scores via 3-term bf16 MFMA (R3 control flow, tiled staging) ----------
__global__ __launch_bounds__(256) void k_scores_mfma(const unsigned short* __restrict__ Qh,
                                                     const unsigned short* __restrict__ Ql,
                                                     const unsigned short* __restrict__ Xh,
                                                     const unsigned short* __restrict__ Xl,
                                                     float* __restrict__ attn) {
    const int t0 = blockIdx.x * 128;
    const int s0 = blockIdx.y * 128;
    if (s0 > t0) return;                      // never read by softmax
    const int b = blockIdx.z;
    __shared__ __align__(16) unsigned short Ah[4][128][8], Al[4][128][8], Bh[4][128][8], Bl[4][128][8];
    const int tid = threadIdx.x, lane = tid & 63, w = tid >> 6;
    const int t_off = (w >> 1) * 64, s_off = (w & 1) * 64;
    const int l15 = lane & 15, lg = lane >> 4;
    const int ablk = b * (T_DIM / 128) + (t0 >> 7);
    const int bblk = b * (T_DIM / 128) + (s0 >> 7);
    f32x4 acc[4][4] = {};

    for (int ks = 0; ks < NKB; ++ks) {
        if (ks) __syncthreads();
        if      (w == 0) stage_tile(Qh + tile_off(ablk, ks), &Ah[0][0][0], lane);
        else if (w == 1) stage_tile(Ql + tile_off(ablk, ks), &Al[0][0][0], lane);
        else if (w == 2) stage_tile(Xh + tile_off(bblk, ks), &Bh[0][0][0], lane);
        else             stage_tile(Xl + tile_off(bblk, ks), &Bl[0][0][0], lane);
        __syncthreads();

        bf16x8 ah[4], al[4], bh[4], bl[4];
#pragma unroll
        for (int i2 = 0; i2 < 4; ++i2) {
            ah[i2] = *(const bf16x8*)&Ah[lg][t_off + i2 * 16 + l15][0];
            al[i2] = *(const bf16x8*)&Al[lg][t_off + i2 * 16 + l15][0];
        }
#pragma unroll
        for (int j = 0; j < 4; ++j) {
            bh[j] = *(const bf16x8*)&Bh[lg][s_off + j * 16 + l15][0];
            bl[j] = *(const bf16x8*)&Bl[lg][s_off + j * 16 + l15][0];
        }
#pragma unroll
        for (int i2 = 0; i2 < 4; ++i2)
#pragma unroll
            for (int j = 0; j < 4; ++j) {
                acc[i2][j] = __builtin_amdgcn_mfma_f32_16x16x32_bf16(ah[i2], bh[j], acc[i2][j], 0, 0, 0);
                acc[i2][j] = __builtin_amdgcn_mfma_f32_16x16x32_bf16(al[i2], bh[j], acc[i2][j], 0, 0, 0);
                acc[i2][j] = __builtin_amdgcn_mfma_f32_16x16x32_bf16(ah[i2], bl[j], acc[i2][j], 0, 0, 0);
            }
    }

    float* base = attn + (size_t)b * T_DIM * T_DIM;
#pragma unroll
    for (int i2 = 0; i2 < 4; ++i2)
#pragma unroll
        for (int j = 0; j < 4; ++j)
#pragma unroll
            for (int r = 0; r < 4; ++r) {
                int t = t0 + t_off + i2 * 16 + lg * 4 + r;
                int s = s0 + s_off + j * 16 + l15;
                base[(size_t)t * T_DIM + s] = acc[i2][j][r];
            }
}

// ---------- Kernel 5: in-place masked softmax per (b,t) row ----------
__global__ __launch_bounds__(256) void k_softmax(float* __restrict__ attn) {
    const int row = blockIdx.x;
    const int t = row & (T_DIM - 1);
    float* p = attn + (size_t)row * T_DIM;
    const int tid = threadIdx.x;
    const int n = (t >= 2) ? t : 0;
    __shared__ float red[4];

    if (n == 0) {
        const float4 z = {0.f, 0.f, 0.f, 0.f};
        for (int s = tid * 4; s < T_DIM; s += 1024) *(float4*)&p[s] = z;
        return;
    }

    float m = -INFINITY;
    for (int s = tid; s < n; s += 256) m = fmaxf(m, p[s]);
#pragma unroll
    for (int off = 32; off >= 1; off >>= 1) m = fmaxf(m, __shfl_xor(m, off));
    if ((tid & 63) == 0) red[tid >> 6] = m;
    __syncthreads();
    m = fmaxf(fmaxf(red[0], red[1]), fmaxf(red[2], red[3]));
    __syncthreads();

    float sum = 0.f;
    for (int s = tid; s < n; s += 256) sum += expf(p[s] - m);
#pragma unroll
    for (int off = 32; off >= 1; off >>= 1) sum += __shfl_xor(sum, off);
    if ((tid & 63) == 0) red[tid >> 6] = sum;
    __syncthreads();
    sum = red[0] + red[1] + red[2] + red[3];
    const float inv = 1.f / sum;

    for (int s = tid * 4; s < T_DIM; s += 1024) {
        float4 o = {0.f, 0.f, 0.f, 0.f};
        if (s + 3 < n) {
            float4 v = *(float4*)&p[s];
            o.x = expf(v.x - m) * inv;
            o.y = expf(v.y - m) * inv;
            o.z = expf(v.z - m) * inv;
            o.w = expf(v.w - m) * inv;
        } else if (s < n) {
            float tmp[4] = {0.f, 0.f, 0.f, 0.f};
            for (int j = 0; j < 4; ++j)
                if (s + j < n) tmp[j] = expf(p[s + j] - m) * inv;
            o.x = tmp[0]; o.y = tmp[1]; o.z = tmp[2]; o.w = tmp[3];
        }
        *(float4*)&p[s] = o;
    }
}

extern "C" void kernel_launch(void* const* d_in, const int* in_sizes, int n_in,
                              void* d_out, int out_size, void* d_ws, size_t ws_size,
                              hipStream_t stream) {
    const float* inputs   = (const float*)d_in[0];   // [T,B,H]
    const float* rand_ctx = (const float*)d_in[1];   // [T,B,H]
    const float* W        = (const float*)d_in[2];   // [H,H]
    float* out  = (float*)d_out;
    float* attn = out + (size_t)T_DIM * B_DIM * 2 * H_DIM;

    unsigned short* Xh  = (unsigned short*)d_ws;
    unsigned short* Xl  = Xh + (size_t)16777216;
    unsigned short* Qh  = Xh + (size_t)33554432;
    unsigned short* Ql  = Xh + (size_t)50331648;
    unsigned short* Wth = Xh + (size_t)67108864;
    unsigned short* Wtl = Wth + (size_t)262144;

    k_prep<<<dim3(T_DIM * B_DIM * 64 / 256), dim3(256), 0, stream>>>(
        inputs, rand_ctx, out, Xh, Xl);

    k_split_w<<<dim3(128), dim3(256), 0, stream>>>(W, Wth, Wtl);

    k_qgemm_mfma<<<dim3(T_DIM * B_DIM / 128, H_DIM / 128), dim3(256), 0, stream>>>(
        Xh, Xl, Wth, Wtl, Qh, Ql);

    k_scores_mfma<<<dim3(T_DIM / 128, T_DIM / 128, B_DIM), dim3(256), 0, stream>>>(
        Qh, Ql, Xh, Xl, attn);

    k_softmax<<<dim3(B_DIM * T_DIM), dim3(256), 0, stream>>>(attn);
}

// Round 7
// 397.337 us; speedup vs baseline: 1.9976x; 1.1852x over previous
//
#include <hip/hip_runtime.h>
#include <math.h>

#define T_DIM 2048
#define B_DIM 16
#define H_DIM 512
#define NKB   (H_DIM / 32)   // 16 k-blocks of 32
// out: results [T,B,2H] (33,554,432 f32) then attn [B,T,T] (67,108,864 f32)
// ws (ushort = fp16 bits), arrays TILED: tile(rowblk,kblk) = 8KB as [g(4)][row(128)][8]
// — byte-identical to the LDS image, staging is a linear coalesced copy.
//   Xh @0 (16Mi), Xl @16Mi, Qh @32Mi, Ql @48Mi, Wth @64Mi (256Ki). (~128.5 MB)

typedef _Float16 f16x8 __attribute__((ext_vector_type(8)));
typedef float f32x4 __attribute__((ext_vector_type(4)));

__device__ __forceinline__ unsigned short h_bits(_Float16 h) {
    unsigned short u; __builtin_memcpy(&u, &h, 2); return u;
}

__device__ __forceinline__ size_t tile_off(int rowblk, int kblk) {
    return ((size_t)rowblk * NKB + kblk) * 4096;   // 4096 ushorts = 8KB per tile
}
__device__ __forceinline__ size_t tiled_idx(int r, int c) {
    return tile_off(r >> 7, c >> 5) + (size_t)((c >> 3) & 3) * 1024 + (size_t)(r & 127) * 8 + (c & 7);
}

// fp16 hi/lo split of 8 floats -> packed uint4 hi, uint4 lo
__device__ __forceinline__ void split8h(const float* xs, uint4* ho, uint4* lo) {
    unsigned int hw[4], lw[4];
#pragma unroll
    for (int e = 0; e < 4; ++e) {
        _Float16 h0 = (_Float16)xs[2 * e], h1 = (_Float16)xs[2 * e + 1];
        _Float16 l0 = (_Float16)(xs[2 * e] - (float)h0);
        _Float16 l1 = (_Float16)(xs[2 * e + 1] - (float)h1);
        hw[e] = (unsigned int)h_bits(h0) | ((unsigned int)h_bits(h1) << 16);
        lw[e] = (unsigned int)h_bits(l0) | ((unsigned int)h_bits(l1) << 16);
    }
    *ho = make_uint4(hw[0], hw[1], hw[2], hw[3]);
    *lo = make_uint4(lw[0], lw[1], lw[2], lw[3]);
}

// ---------- Kernel 1: results copy + X split to fp16 hi/lo (tiled, batch-major) ----------
__global__ __launch_bounds__(256) void k_prep(const float* __restrict__ X,
                                              const float* __restrict__ RC,
                                              float* __restrict__ out,
                                              unsigned short* __restrict__ Xh,
                                              unsigned short* __restrict__ Xl) {
    int i = blockIdx.x * 256 + threadIdx.x;
    int row = i >> 6;                 // t*B + b
    int h0 = (i & 63) * 8;
    int t = row >> 4;
    int b = row & 15;
    const float* xp = X + (size_t)row * H_DIM + h0;
    float4 v0 = *(const float4*)xp;
    float4 v1 = *(const float4*)(xp + 4);
    float* op = out + (size_t)row * (2 * H_DIM) + h0;
    *(float4*)op = v0;
    *(float4*)(op + 4) = v1;
    const float* cp = RC + (size_t)row * H_DIM + h0;
    float4 c0 = *(const float4*)cp;
    float4 c1 = *(const float4*)(cp + 4);
    if (t < 2) { c0 = v0; c1 = v1; }
    *(float4*)(op + H_DIM) = c0;
    *(float4*)(op + H_DIM + 4) = c1;
    float xs[8] = {v0.x, v0.y, v0.z, v0.w, v1.x, v1.y, v1.z, v1.w};
    uint4 ho, lo;
    split8h(xs, &ho, &lo);
    int r = b * T_DIM + t;            // batch-major row index
    size_t dst = tiled_idx(r, h0);    // h0 % 8 == 0 -> 16B aligned
    *(uint4*)(Xh + dst) = ho;
    *(uint4*)(Xl + dst) = lo;
}

// ---------- Kernel 2: W -> transposed fp16 hi only, tiled [n][k] ----------
__global__ __launch_bounds__(256) void k_split_w(const float* __restrict__ W,
                                                 unsigned short* __restrict__ Wth) {
    int i = blockIdx.x * 256 + threadIdx.x;
    int n = i & 511;
    int k0 = (i >> 9) * 8;
    unsigned int hw[4];
#pragma unroll
    for (int e = 0; e < 4; ++e) {
        _Float16 h0 = (_Float16)W[(size_t)(k0 + 2 * e) * H_DIM + n];
        _Float16 h1 = (_Float16)W[(size_t)(k0 + 2 * e + 1) * H_DIM + n];
        hw[e] = (unsigned int)h_bits(h0) | ((unsigned int)h_bits(h1) << 16);
    }
    size_t dst = tiled_idx(n, k0);
    *(uint4*)(Wth + dst) = make_uint4(hw[0], hw[1], hw[2], hw[3]);
}

// ---------- staging: one pre-tiled 8KB tile -> LDS, linear copy, fully coalesced ----------
__device__ __forceinline__ void stage_tile(const unsigned short* __restrict__ src_tile,
                                           unsigned short* lds_base, int lane) {
#pragma unroll
    for (int c = 0; c < 8; ++c) {
        __builtin_amdgcn_global_load_lds(
            (const __attribute__((address_space(1))) void*)(src_tile + c * 512 + lane * 8),
            (__attribute__((address_space(3))) void*)(lds_base + c * 512),
            16, 0, 0);
    }
}

// ---------- Kernel 3: Q = X @ W via 2-pass fp16 MFMA ----------
// grid: 1024 linear, XCD-swizzled so the 4 n-blocks of one m-block are consecutive
// on one XCD (X row-block fetched once; W is L2-resident).
__global__ __launch_bounds__(256) void k_qgemm_mfma(const unsigned short* __restrict__ Xh,
                                                    const unsigned short* __restrict__ Xl,
                                                    const unsigned short* __restrict__ Wth,
                                                    unsigned short* __restrict__ Qh,
                                                    unsigned short* __restrict__ Ql) {
    __shared__ __align__(16) unsigned short Ah[4][128][8], Al[4][128][8], Bh[4][128][8];
    const int bid = blockIdx.x;                       // 1024 = 8 * 128
    const int swz = (bid & 7) * 128 + (bid >> 3);     // bijective
    const int mblk = swz >> 2, nblk = swz & 3;
    const int m0 = mblk * 128, n0 = nblk * 128;
    const int tid = threadIdx.x, lane = tid & 63, w = tid >> 6;
    const int t_off = (w >> 1) * 64, s_off = (w & 1) * 64;
    const int l15 = lane & 15, lg = lane >> 4;
    f32x4 acc[4][4] = {};

    for (int ks = 0; ks < NKB; ++ks) {
        if (ks) __syncthreads();
        if      (w == 0) stage_tile(Xh  + tile_off(mblk, ks), &Ah[0][0][0], lane);
        else if (w == 1) stage_tile(Xl  + tile_off(mblk, ks), &Al[0][0][0], lane);
        else if (w == 2) stage_tile(Wth + tile_off(nblk, ks), &Bh[0][0][0], lane);
        __syncthreads();

        f16x8 ah[4], al[4], bh[4];
#pragma unroll
        for (int i2 = 0; i2 < 4; ++i2) {
            ah[i2] = *(const f16x8*)&Ah[lg][t_off + i2 * 16 + l15][0];
            al[i2] = *(const f16x8*)&Al[lg][t_off + i2 * 16 + l15][0];
        }
#pragma unroll
        for (int j = 0; j < 4; ++j)
            bh[j] = *(const f16x8*)&Bh[lg][s_off + j * 16 + l15][0];
#pragma unroll
        for (int i2 = 0; i2 < 4; ++i2)
#pragma unroll
            for (int j = 0; j < 4; ++j) {
                acc[i2][j] = __builtin_amdgcn_mfma_f32_16x16x32_f16(ah[i2], bh[j], acc[i2][j], 0, 0, 0);
                acc[i2][j] = __builtin_amdgcn_mfma_f32_16x16x32_f16(al[i2], bh[j], acc[i2][j], 0, 0, 0);
            }
    }

    // scatter epilogue (proven pattern), destination tiled, fp16 hi/lo split
#pragma unroll
    for (int i2 = 0; i2 < 4; ++i2)
#pragma unroll
        for (int j = 0; j < 4; ++j)
#pragma unroll
            for (int r = 0; r < 4; ++r) {
                int R = m0 + t_off + i2 * 16 + lg * 4 + r;
                int C = n0 + s_off + j * 16 + l15;
                float q = acc[i2][j][r];
                _Float16 qh = (_Float16)q;
                _Float16 ql = (_Float16)(q - (float)qh);
                size_t dst = tiled_idx(R, C);
                Qh[dst] = h_bits(qh);
                Ql[dst] = h_bits(ql);
            }
}

// ---------- Kernel 4: scores via 2-pass fp16 MFMA, triangle grid + XCD swizzle ----------
__global__ __launch_bounds__(256) void k_scores_mfma(const unsigned short* __restrict__ Qh,
                                                     const unsigned short* __restrict__ Ql,
                                                     const unsigned short* __restrict__ Xh,
                                                     float* __restrict__ attn) {
    // 2176 live blocks = 16 batches x 136 triangle tile-pairs; 2176 = 8 * 272
    const int bid = blockIdx.x;
    const int swz = (bid & 7) * 272 + (bid >> 3);     // bijective XCD chunking
    const int b = swz / 136;
    const int r = swz - b * 136;
    int ti = (int)((sqrtf(8.f * (float)r + 1.f) - 1.f) * 0.5f);
    while ((ti + 1) * (ti + 2) / 2 <= r) ++ti;
    while (ti * (ti + 1) / 2 > r) --ti;
    const int si = r - ti * (ti + 1) / 2;             // si <= ti
    const int t0 = ti * 128, s0 = si * 128;

    __shared__ __align__(16) unsigned short Ah[4][128][8], Al[4][128][8], Bh[4][128][8];
    const int tid = threadIdx.x, lane = tid & 63, w = tid >> 6;
    const int t_off = (w >> 1) * 64, s_off = (w & 1) * 64;
    const int l15 = lane & 15, lg = lane >> 4;
    const int ablk = b * (T_DIM / 128) + ti;
    const int bblk = b * (T_DIM / 128) + si;
    f32x4 acc[4][4] = {};

    for (int ks = 0; ks < NKB; ++ks) {
        if (ks) __syncthreads();
        if      (w == 0) stage_tile(Qh + tile_off(ablk, ks), &Ah[0][0][0], lane);
        else if (w == 1) stage_tile(Ql + tile_off(ablk, ks), &Al[0][0][0], lane);
        else if (w == 2) stage_tile(Xh + tile_off(bblk, ks), &Bh[0][0][0], lane);
        __syncthreads();

        f16x8 ah[4], al[4], bh[4];
#pragma unroll
        for (int i2 = 0; i2 < 4; ++i2) {
            ah[i2] = *(const f16x8*)&Ah[lg][t_off + i2 * 16 + l15][0];
            al[i2] = *(const f16x8*)&Al[lg][t_off + i2 * 16 + l15][0];
        }
#pragma unroll
        for (int j = 0; j < 4; ++j)
            bh[j] = *(const f16x8*)&Bh[lg][s_off + j * 16 + l15][0];
#pragma unroll
        for (int i2 = 0; i2 < 4; ++i2)
#pragma unroll
            for (int j = 0; j < 4; ++j) {
                acc[i2][j] = __builtin_amdgcn_mfma_f32_16x16x32_f16(ah[i2], bh[j], acc[i2][j], 0, 0, 0);
                acc[i2][j] = __builtin_amdgcn_mfma_f32_16x16x32_f16(al[i2], bh[j], acc[i2][j], 0, 0, 0);
            }
    }

    float* base = attn + (size_t)b * T_DIM * T_DIM;
#pragma unroll
    for (int i2 = 0; i2 < 4; ++i2)
#pragma unroll
        for (int j = 0; j < 4; ++j)
#pragma unroll
            for (int rr = 0; rr < 4; ++rr) {
                int t = t0 + t_off + i2 * 16 + lg * 4 + rr;
                int s = s0 + s_off + j * 16 + l15;
                base[(size_t)t * T_DIM + s] = acc[i2][j][rr];
            }
}

// ---------- Kernel 5: in-place masked softmax per (b,t) row ----------
__global__ __launch_bounds__(256) void k_softmax(float* __restrict__ attn) {
    const int row = blockIdx.x;
    const int t = row & (T_DIM - 1);
    float* p = attn + (size_t)row * T_DIM;
    const int tid = threadIdx.x;
    const int n = (t >= 2) ? t : 0;
    __shared__ float red[4];

    if (n == 0) {
        const float4 z = {0.f, 0.f, 0.f, 0.f};
        for (int s = tid * 4; s < T_DIM; s += 1024) *(float4*)&p[s] = z;
        return;
    }

    float m = -INFINITY;
    for (int s = tid; s < n; s += 256) m = fmaxf(m, p[s]);
#pragma unroll
    for (int off = 32; off >= 1; off >>= 1) m = fmaxf(m, __shfl_xor(m, off));
    if ((tid & 63) == 0) red[tid >> 6] = m;
    __syncthreads();
    m = fmaxf(fmaxf(red[0], red[1]), fmaxf(red[2], red[3]));
    __syncthreads();

    float sum = 0.f;
    for (int s = tid; s < n; s += 256) sum += expf(p[s] - m);
#pragma unroll
    for (int off = 32; off >= 1; off >>= 1) sum += __shfl_xor(sum, off);
    if ((tid & 63) == 0) red[tid >> 6] = sum;
    __syncthreads();
    sum = red[0] + red[1] + red[2] + red[3];
    const float inv = 1.f / sum;

    for (int s = tid * 4; s < T_DIM; s += 1024) {
        float4 o = {0.f, 0.f, 0.f, 0.f};
        if (s + 3 < n) {
            float4 v = *(float4*)&p[s];
            o.x = expf(v.x - m) * inv;
            o.y = expf(v.y - m) * inv;
            o.z = expf(v.z - m) * inv;
            o.w = expf(v.w - m) * inv;
        } else if (s < n) {
            float tmp[4] = {0.f, 0.f, 0.f, 0.f};
            for (int j = 0; j < 4; ++j)
                if (s + j < n) tmp[j] = expf(p[s + j] - m) * inv;
            o.x = tmp[0]; o.y = tmp[1]; o.z = tmp[2]; o.w = tmp[3];
        }
        *(float4*)&p[s] = o;
    }
}

extern "C" void kernel_launch(void* const* d_in, const int* in_sizes, int n_in,
                              void* d_out, int out_size, void* d_ws, size_t ws_size,
                              hipStream_t stream) {
    const float* inputs   = (const float*)d_in[0];   // [T,B,H]
    const float* rand_ctx = (const float*)d_in[1];   // [T,B,H]
    const float* W        = (const float*)d_in[2];   // [H,H]
    float* out  = (float*)d_out;
    float* attn = out + (size_t)T_DIM * B_DIM * 2 * H_DIM;

    unsigned short* Xh  = (unsigned short*)d_ws;
    unsigned short* Xl  = Xh + (size_t)16777216;
    unsigned short* Qh  = Xh + (size_t)33554432;
    unsigned short* Ql  = Xh + (size_t)50331648;
    unsigned short* Wth = Xh + (size_t)67108864;

    k_prep<<<dim3(T_DIM * B_DIM * 64 / 256), dim3(256), 0, stream>>>(
        inputs, rand_ctx, out, Xh, Xl);

    k_split_w<<<dim3(128), dim3(256), 0, stream>>>(W, Wth);

    k_qgemm_mfma<<<dim3(1024), dim3(256), 0, stream>>>(Xh, Xl, Wth, Qh, Ql);

    k_scores_mfma<<<dim3(2176), dim3(256), 0, stream>>>(Qh, Ql, Xh, attn);

    k_softmax<<<dim3(B_DIM * T_DIM), dim3(256), 0, stream>>>(attn);
}

// Round 8
// 364.559 us; speedup vs baseline: 2.1772x; 1.0899x over previous
//
#include <hip/hip_runtime.h>
#include <math.h>

#define T_DIM 2048
#define B_DIM 16
#define H_DIM 512
#define NKB   (H_DIM / 32)   // 16 k-blocks of 32
// out: results [T,B,2H] (33,554,432 f32) then attn [B,T,T] (67,108,864 f32)
// ws (ushort = fp16 bits), arrays TILED: tile(rowblk,kblk) = 8KB as [g(4)][row(128)][8]
// — byte-identical to the LDS image, staging is a linear coalesced copy.
//   Xh @0 (16Mi), Xl @16Mi, Qh @32Mi, (Ql slot unused), Wth @64Mi (256Ki).

typedef _Float16 f16x8 __attribute__((ext_vector_type(8)));
typedef float f32x4 __attribute__((ext_vector_type(4)));

__device__ __forceinline__ unsigned short h_bits(_Float16 h) {
    unsigned short u; __builtin_memcpy(&u, &h, 2); return u;
}

__device__ __forceinline__ size_t tile_off(int rowblk, int kblk) {
    return ((size_t)rowblk * NKB + kblk) * 4096;   // 4096 ushorts = 8KB per tile
}
__device__ __forceinline__ size_t tiled_idx(int r, int c) {
    return tile_off(r >> 7, c >> 5) + (size_t)((c >> 3) & 3) * 1024 + (size_t)(r & 127) * 8 + (c & 7);
}

// fp16 hi/lo split of 8 floats -> packed uint4 hi, uint4 lo
__device__ __forceinline__ void split8h(const float* xs, uint4* ho, uint4* lo) {
    unsigned int hw[4], lw[4];
#pragma unroll
    for (int e = 0; e < 4; ++e) {
        _Float16 h0 = (_Float16)xs[2 * e], h1 = (_Float16)xs[2 * e + 1];
        _Float16 l0 = (_Float16)(xs[2 * e] - (float)h0);
        _Float16 l1 = (_Float16)(xs[2 * e + 1] - (float)h1);
        hw[e] = (unsigned int)h_bits(h0) | ((unsigned int)h_bits(h1) << 16);
        lw[e] = (unsigned int)h_bits(l0) | ((unsigned int)h_bits(l1) << 16);
    }
    *ho = make_uint4(hw[0], hw[1], hw[2], hw[3]);
    *lo = make_uint4(lw[0], lw[1], lw[2], lw[3]);
}

// ---------- Kernel 1: results copy + X split to fp16 hi/lo (tiled, batch-major) ----------
__global__ __launch_bounds__(256) void k_prep(const float* __restrict__ X,
                                              const float* __restrict__ RC,
                                              float* __restrict__ out,
                                              unsigned short* __restrict__ Xh,
                                              unsigned short* __restrict__ Xl) {
    int i = blockIdx.x * 256 + threadIdx.x;
    int row = i >> 6;                 // t*B + b
    int h0 = (i & 63) * 8;
    int t = row >> 4;
    int b = row & 15;
    const float* xp = X + (size_t)row * H_DIM + h0;
    float4 v0 = *(const float4*)xp;
    float4 v1 = *(const float4*)(xp + 4);
    float* op = out + (size_t)row * (2 * H_DIM) + h0;
    *(float4*)op = v0;
    *(float4*)(op + 4) = v1;
    const float* cp = RC + (size_t)row * H_DIM + h0;
    float4 c0 = *(const float4*)cp;
    float4 c1 = *(const float4*)(cp + 4);
    if (t < 2) { c0 = v0; c1 = v1; }
    *(float4*)(op + H_DIM) = c0;
    *(float4*)(op + H_DIM + 4) = c1;
    float xs[8] = {v0.x, v0.y, v0.z, v0.w, v1.x, v1.y, v1.z, v1.w};
    uint4 ho, lo;
    split8h(xs, &ho, &lo);
    int r = b * T_DIM + t;            // batch-major row index
    size_t dst = tiled_idx(r, h0);    // h0 % 8 == 0 -> 16B aligned
    *(uint4*)(Xh + dst) = ho;
    *(uint4*)(Xl + dst) = lo;
}

// ---------- Kernel 2: W -> transposed fp16 hi only, tiled [n][k] ----------
__global__ __launch_bounds__(256) void k_split_w(const float* __restrict__ W,
                                                 unsigned short* __restrict__ Wth) {
    int i = blockIdx.x * 256 + threadIdx.x;
    int n = i & 511;
    int k0 = (i >> 9) * 8;
    unsigned int hw[4];
#pragma unroll
    for (int e = 0; e < 4; ++e) {
        _Float16 h0 = (_Float16)W[(size_t)(k0 + 2 * e) * H_DIM + n];
        _Float16 h1 = (_Float16)W[(size_t)(k0 + 2 * e + 1) * H_DIM + n];
        hw[e] = (unsigned int)h_bits(h0) | ((unsigned int)h_bits(h1) << 16);
    }
    size_t dst = tiled_idx(n, k0);
    *(uint4*)(Wth + dst) = make_uint4(hw[0], hw[1], hw[2], hw[3]);
}

// ---------- staging: one pre-tiled 8KB tile -> LDS, linear copy, fully coalesced ----------
__device__ __forceinline__ void stage_tile(const unsigned short* __restrict__ src_tile,
                                           unsigned short* lds_base, int lane) {
#pragma unroll
    for (int c = 0; c < 8; ++c) {
        __builtin_amdgcn_global_load_lds(
            (const __attribute__((address_space(1))) void*)(src_tile + c * 512 + lane * 8),
            (__attribute__((address_space(3))) void*)(lds_base + c * 512),
            16, 0, 0);
    }
}
// half-tile variant: chunks [h*4, h*4+4) of an 8KB tile
__device__ __forceinline__ void stage_half(const unsigned short* __restrict__ src_tile,
                                           unsigned short* lds_base, int lane, int h) {
#pragma unroll
    for (int c = 0; c < 4; ++c) {
        const int ch = h * 4 + c;
        __builtin_amdgcn_global_load_lds(
            (const __attribute__((address_space(1))) void*)(src_tile + ch * 512 + lane * 8),
            (__attribute__((address_space(3))) void*)(lds_base + ch * 512),
            16, 0, 0);
    }
}

// ---------- Kernel 3: Q = X @ W via 2-pass fp16 MFMA (R7-proven), hi-only output ----------
__global__ __launch_bounds__(256) void k_qgemm_mfma(const unsigned short* __restrict__ Xh,
                                                    const unsigned short* __restrict__ Xl,
                                                    const unsigned short* __restrict__ Wth,
                                                    unsigned short* __restrict__ Qh) {
    __shared__ __align__(16) unsigned short Ah[4][128][8], Al[4][128][8], Bh[4][128][8];
    const int bid = blockIdx.x;                       // 1024 = 8 * 128
    const int swz = (bid & 7) * 128 + (bid >> 3);     // bijective
    const int mblk = swz >> 2, nblk = swz & 3;
    const int m0 = mblk * 128, n0 = nblk * 128;
    const int tid = threadIdx.x, lane = tid & 63, w = tid >> 6;
    const int t_off = (w >> 1) * 64, s_off = (w & 1) * 64;
    const int l15 = lane & 15, lg = lane >> 4;
    f32x4 acc[4][4] = {};

    for (int ks = 0; ks < NKB; ++ks) {
        if (ks) __syncthreads();
        if      (w == 0) stage_tile(Xh  + tile_off(mblk, ks), &Ah[0][0][0], lane);
        else if (w == 1) stage_tile(Xl  + tile_off(mblk, ks), &Al[0][0][0], lane);
        else if (w == 2) stage_tile(Wth + tile_off(nblk, ks), &Bh[0][0][0], lane);
        __syncthreads();

        f16x8 ah[4], al[4], bh[4];
#pragma unroll
        for (int i2 = 0; i2 < 4; ++i2) {
            ah[i2] = *(const f16x8*)&Ah[lg][t_off + i2 * 16 + l15][0];
            al[i2] = *(const f16x8*)&Al[lg][t_off + i2 * 16 + l15][0];
        }
#pragma unroll
        for (int j = 0; j < 4; ++j)
            bh[j] = *(const f16x8*)&Bh[lg][s_off + j * 16 + l15][0];
#pragma unroll
        for (int i2 = 0; i2 < 4; ++i2)
#pragma unroll
            for (int j = 0; j < 4; ++j) {
                acc[i2][j] = __builtin_amdgcn_mfma_f32_16x16x32_f16(ah[i2], bh[j], acc[i2][j], 0, 0, 0);
                acc[i2][j] = __builtin_amdgcn_mfma_f32_16x16x32_f16(al[i2], bh[j], acc[i2][j], 0, 0, 0);
            }
    }

    // scatter epilogue (proven pattern), hi-only fp16 output
#pragma unroll
    for (int i2 = 0; i2 < 4; ++i2)
#pragma unroll
        for (int j = 0; j < 4; ++j)
#pragma unroll
            for (int r = 0; r < 4; ++r) {
                int R = m0 + t_off + i2 * 16 + lg * 4 + r;
                int C = n0 + s_off + j * 16 + l15;
                _Float16 qh = (_Float16)acc[i2][j][r];
                Qh[tiled_idx(R, C)] = h_bits(qh);
            }
}

// ---------- Kernel 4: scores via SINGLE-pass fp16 MFMA, triangle grid + XCD swizzle ----------
__global__ __launch_bounds__(256) void k_scores_mfma(const unsigned short* __restrict__ Qh,
                                                     const unsigned short* __restrict__ Xh,
                                                     float* __restrict__ attn) {
    // 2176 live blocks = 16 batches x 136 triangle tile-pairs; 2176 = 8 * 272
    const int bid = blockIdx.x;
    const int swz = (bid & 7) * 272 + (bid >> 3);     // bijective XCD chunking
    const int b = swz / 136;
    const int r = swz - b * 136;
    int ti = (int)((sqrtf(8.f * (float)r + 1.f) - 1.f) * 0.5f);
    while ((ti + 1) * (ti + 2) / 2 <= r) ++ti;
    while (ti * (ti + 1) / 2 > r) --ti;
    const int si = r - ti * (ti + 1) / 2;             // si <= ti
    const int t0 = ti * 128, s0 = si * 128;

    __shared__ __align__(16) unsigned short Ah[4][128][8], Bh[4][128][8];
    const int tid = threadIdx.x, lane = tid & 63, w = tid >> 6;
    const int t_off = (w >> 1) * 64, s_off = (w & 1) * 64;
    const int l15 = lane & 15, lg = lane >> 4;
    const int ablk = b * (T_DIM / 128) + ti;
    const int bblk = b * (T_DIM / 128) + si;
    f32x4 acc[4][4] = {};

    for (int ks = 0; ks < NKB; ++ks) {
        if (ks) __syncthreads();
        // 16 chunks over 4 waves: w0/w1 -> A halves, w2/w3 -> B halves
        if (w < 2) stage_half(Qh + tile_off(ablk, ks), &Ah[0][0][0], lane, w);
        else       stage_half(Xh + tile_off(bblk, ks), &Bh[0][0][0], lane, w - 2);
        __syncthreads();

        f16x8 ah[4], bh[4];
#pragma unroll
        for (int i2 = 0; i2 < 4; ++i2)
            ah[i2] = *(const f16x8*)&Ah[lg][t_off + i2 * 16 + l15][0];
#pragma unroll
        for (int j = 0; j < 4; ++j)
            bh[j] = *(const f16x8*)&Bh[lg][s_off + j * 16 + l15][0];
#pragma unroll
        for (int i2 = 0; i2 < 4; ++i2)
#pragma unroll
            for (int j = 0; j < 4; ++j)
                acc[i2][j] = __builtin_amdgcn_mfma_f32_16x16x32_f16(ah[i2], bh[j], acc[i2][j], 0, 0, 0);
    }

    float* base = attn + (size_t)b * T_DIM * T_DIM;
#pragma unroll
    for (int i2 = 0; i2 < 4; ++i2)
#pragma unroll
        for (int j = 0; j < 4; ++j)
#pragma unroll
            for (int rr = 0; rr < 4; ++rr) {
                int t = t0 + t_off + i2 * 16 + lg * 4 + rr;
                int s = s0 + s_off + j * 16 + l15;
                base[(size_t)t * T_DIM + s] = acc[i2][j][rr];
            }
}

// ---------- Kernel 5: in-place masked softmax per (b,t) row ----------
__global__ __launch_bounds__(256) void k_softmax(float* __restrict__ attn) {
    const int row = blockIdx.x;
    const int t = row & (T_DIM - 1);
    float* p = attn + (size_t)row * T_DIM;
    const int tid = threadIdx.x;
    const int n = (t >= 2) ? t : 0;
    __shared__ float red[4];

    if (n == 0) {
        const float4 z = {0.f, 0.f, 0.f, 0.f};
        for (int s = tid * 4; s < T_DIM; s += 1024) *(float4*)&p[s] = z;
        return;
    }

    float m = -INFINITY;
    for (int s = tid; s < n; s += 256) m = fmaxf(m, p[s]);
#pragma unroll
    for (int off = 32; off >= 1; off >>= 1) m = fmaxf(m, __shfl_xor(m, off));
    if ((tid & 63) == 0) red[tid >> 6] = m;
    __syncthreads();
    m = fmaxf(fmaxf(red[0], red[1]), fmaxf(red[2], red[3]));
    __syncthreads();

    float sum = 0.f;
    for (int s = tid; s < n; s += 256) sum += expf(p[s] - m);
#pragma unroll
    for (int off = 32; off >= 1; off >>= 1) sum += __shfl_xor(sum, off);
    if ((tid & 63) == 0) red[tid >> 6] = sum;
    __syncthreads();
    sum = red[0] + red[1] + red[2] + red[3];
    const float inv = 1.f / sum;

    for (int s = tid * 4; s < T_DIM; s += 1024) {
        float4 o = {0.f, 0.f, 0.f, 0.f};
        if (s + 3 < n) {
            float4 v = *(float4*)&p[s];
            o.x = expf(v.x - m) * inv;
            o.y = expf(v.y - m) * inv;
            o.z = expf(v.z - m) * inv;
            o.w = expf(v.w - m) * inv;
        } else if (s < n) {
            float tmp[4] = {0.f, 0.f, 0.f, 0.f};
            for (int j = 0; j < 4; ++j)
                if (s + j < n) tmp[j] = expf(p[s + j] - m) * inv;
            o.x = tmp[0]; o.y = tmp[1]; o.z = tmp[2]; o.w = tmp[3];
        }
        *(float4*)&p[s] = o;
    }
}

extern "C" void kernel_launch(void* const* d_in, const int* in_sizes, int n_in,
                              void* d_out, int out_size, void* d_ws, size_t ws_size,
                              hipStream_t stream) {
    const float* inputs   = (const float*)d_in[0];   // [T,B,H]
    const float* rand_ctx = (const float*)d_in[1];   // [T,B,H]
    const float* W        = (const float*)d_in[2];   // [H,H]
    float* out  = (float*)d_out;
    float* attn = out + (size_t)T_DIM * B_DIM * 2 * H_DIM;

    unsigned short* Xh  = (unsigned short*)d_ws;
    unsigned short* Xl  = Xh + (size_t)16777216;
    unsigned short* Qh  = Xh + (size_t)33554432;
    unsigned short* Wth = Xh + (size_t)67108864;

    k_prep<<<dim3(T_DIM * B_DIM * 64 / 256), dim3(256), 0, stream>>>(
        inputs, rand_ctx, out, Xh, Xl);

    k_split_w<<<dim3(128), dim3(256), 0, stream>>>(W, Wth);

    k_qgemm_mfma<<<dim3(1024), dim3(256), 0, stream>>>(Xh, Xl, Wth, Qh);

    k_scores_mfma<<<dim3(2176), dim3(256), 0, stream>>>(Qh, Xh, attn);

    k_softmax<<<dim3(B_DIM * T_DIM), dim3(256), 0, stream>>>(attn);
}

// Round 9
// 305.783 us; speedup vs baseline: 2.5957x; 1.1922x over previous
//
#include <hip/hip_runtime.h>
#include <math.h>

#define T_DIM 2048
#define B_DIM 16
#define H_DIM 512
#define NKB   (H_DIM / 32)   // 16 k-blocks of 32
// out: results [T,B,2H] (33,554,432 f32) then attn [B,T,T] (67,108,864 f32)
// ws (ushort = fp16 bits), arrays TILED: tile(rowblk,kblk) = 8KB as [g(4)][row(128)][8]
// — byte-identical to the LDS image, staging is a linear coalesced copy.
//   Xh @0 (32MB), Qh @32Mi elems (32MB), Wth @64Mi elems (512KB).

typedef _Float16 f16x8 __attribute__((ext_vector_type(8)));
typedef float f32x4 __attribute__((ext_vector_type(4)));

__device__ __forceinline__ unsigned short h_bits(_Float16 h) {
    unsigned short u; __builtin_memcpy(&u, &h, 2); return u;
}

__device__ __forceinline__ size_t tile_off(int rowblk, int kblk) {
    return ((size_t)rowblk * NKB + kblk) * 4096;   // 4096 ushorts = 8KB per tile
}
__device__ __forceinline__ size_t tiled_idx(int r, int c) {
    return tile_off(r >> 7, c >> 5) + (size_t)((c >> 3) & 3) * 1024 + (size_t)(r & 127) * 8 + (c & 7);
}

// ---------- Kernel 1: results copy + X -> fp16 (tiled, batch-major) ----------
__global__ __launch_bounds__(256) void k_prep(const float* __restrict__ X,
                                              const float* __restrict__ RC,
                                              float* __restrict__ out,
                                              unsigned short* __restrict__ Xh) {
    int i = blockIdx.x * 256 + threadIdx.x;
    int row = i >> 6;                 // t*B + b
    int h0 = (i & 63) * 8;
    int t = row >> 4;
    int b = row & 15;
    const float* xp = X + (size_t)row * H_DIM + h0;
    float4 v0 = *(const float4*)xp;
    float4 v1 = *(const float4*)(xp + 4);
    float* op = out + (size_t)row * (2 * H_DIM) + h0;
    *(float4*)op = v0;
    *(float4*)(op + 4) = v1;
    const float* cp = RC + (size_t)row * H_DIM + h0;
    float4 c0 = *(const float4*)cp;
    float4 c1 = *(const float4*)(cp + 4);
    if (t < 2) { c0 = v0; c1 = v1; }
    *(float4*)(op + H_DIM) = c0;
    *(float4*)(op + H_DIM + 4) = c1;
    float xs[8] = {v0.x, v0.y, v0.z, v0.w, v1.x, v1.y, v1.z, v1.w};
    unsigned int hw[4];
#pragma unroll
    for (int e = 0; e < 4; ++e) {
        _Float16 a = (_Float16)xs[2 * e], bb = (_Float16)xs[2 * e + 1];
        hw[e] = (unsigned int)h_bits(a) | ((unsigned int)h_bits(bb) << 16);
    }
    int r = b * T_DIM + t;            // batch-major row index
    *(uint4*)(Xh + tiled_idx(r, h0)) = make_uint4(hw[0], hw[1], hw[2], hw[3]);
}

// ---------- Kernel 2: W -> transposed fp16, tiled [n][k] ----------
__global__ __launch_bounds__(256) void k_split_w(const float* __restrict__ W,
                                                 unsigned short* __restrict__ Wth) {
    int i = blockIdx.x * 256 + threadIdx.x;
    int n = i & 511;
    int k0 = (i >> 9) * 8;
    unsigned int hw[4];
#pragma unroll
    for (int e = 0; e < 4; ++e) {
        _Float16 h0 = (_Float16)W[(size_t)(k0 + 2 * e) * H_DIM + n];
        _Float16 h1 = (_Float16)W[(size_t)(k0 + 2 * e + 1) * H_DIM + n];
        hw[e] = (unsigned int)h_bits(h0) | ((unsigned int)h_bits(h1) << 16);
    }
    *(uint4*)(Wth + tiled_idx(n, k0)) = make_uint4(hw[0], hw[1], hw[2], hw[3]);
}

// ---------- staging: half of a pre-tiled 8KB tile -> LDS, linear coalesced copy ----------
__device__ __forceinline__ void stage_half(const unsigned short* __restrict__ src_tile,
                                           unsigned short* lds_base, int lane, int h) {
#pragma unroll
    for (int c = 0; c < 4; ++c) {
        const int ch = h * 4 + c;
        __builtin_amdgcn_global_load_lds(
            (const __attribute__((address_space(1))) void*)(src_tile + ch * 512 + lane * 8),
            (__attribute__((address_space(3))) void*)(lds_base + ch * 512),
            16, 0, 0);
    }
}

// ---------- Kernel 3: Q = X @ W via single-pass fp16 MFMA, hi-only output ----------
__global__ __launch_bounds__(256) void k_qgemm_mfma(const unsigned short* __restrict__ Xh,
                                                    const unsigned short* __restrict__ Wth,
                                                    unsigned short* __restrict__ Qh) {
    __shared__ __align__(16) unsigned short Ah[4][128][8], Bh[4][128][8];
    const int bid = blockIdx.x;                       // 1024 = 8 * 128
    const int swz = (bid & 7) * 128 + (bid >> 3);     // bijective
    const int mblk = swz >> 2, nblk = swz & 3;
    const int m0 = mblk * 128, n0 = nblk * 128;
    const int tid = threadIdx.x, lane = tid & 63, w = tid >> 6;
    const int t_off = (w >> 1) * 64, s_off = (w & 1) * 64;
    const int l15 = lane & 15, lg = lane >> 4;
    f32x4 acc[4][4] = {};

    for (int ks = 0; ks < NKB; ++ks) {
        if (ks) __syncthreads();
        if (w < 2) stage_half(Xh  + tile_off(mblk, ks), &Ah[0][0][0], lane, w);
        else       stage_half(Wth + tile_off(nblk, ks), &Bh[0][0][0], lane, w - 2);
        __syncthreads();

        f16x8 ah[4], bh[4];
#pragma unroll
        for (int i2 = 0; i2 < 4; ++i2)
            ah[i2] = *(const f16x8*)&Ah[lg][t_off + i2 * 16 + l15][0];
#pragma unroll
        for (int j = 0; j < 4; ++j)
            bh[j] = *(const f16x8*)&Bh[lg][s_off + j * 16 + l15][0];
#pragma unroll
        for (int i2 = 0; i2 < 4; ++i2)
#pragma unroll
            for (int j = 0; j < 4; ++j)
                acc[i2][j] = __builtin_amdgcn_mfma_f32_16x16x32_f16(ah[i2], bh[j], acc[i2][j], 0, 0, 0);
    }

    // scatter epilogue (proven pattern), hi-only fp16 output
#pragma unroll
    for (int i2 = 0; i2 < 4; ++i2)
#pragma unroll
        for (int j = 0; j < 4; ++j)
#pragma unroll
            for (int r = 0; r < 4; ++r) {
                int R = m0 + t_off + i2 * 16 + lg * 4 + r;
                int C = n0 + s_off + j * 16 + l15;
                _Float16 qh = (_Float16)acc[i2][j][r];
                Qh[tiled_idx(R, C)] = h_bits(qh);
            }
}

// ---------- Kernel 4: scores via single-pass fp16 MFMA (R8-proven, unchanged) ----------
__global__ __launch_bounds__(256) void k_scores_mfma(const unsigned short* __restrict__ Qh,
                                                     const unsigned short* __restrict__ Xh,
                                                     float* __restrict__ attn) {
    // 2176 live blocks = 16 batches x 136 triangle tile-pairs; 2176 = 8 * 272
    const int bid = blockIdx.x;
    const int swz = (bid & 7) * 272 + (bid >> 3);     // bijective XCD chunking
    const int b = swz / 136;
    const int r = swz - b * 136;
    int ti = (int)((sqrtf(8.f * (float)r + 1.f) - 1.f) * 0.5f);
    while ((ti + 1) * (ti + 2) / 2 <= r) ++ti;
    while (ti * (ti + 1) / 2 > r) --ti;
    const int si = r - ti * (ti + 1) / 2;             // si <= ti
    const int t0 = ti * 128, s0 = si * 128;

    __shared__ __align__(16) unsigned short Ah[4][128][8], Bh[4][128][8];
    const int tid = threadIdx.x, lane = tid & 63, w = tid >> 6;
    const int t_off = (w >> 1) * 64, s_off = (w & 1) * 64;
    const int l15 = lane & 15, lg = lane >> 4;
    const int ablk = b * (T_DIM / 128) + ti;
    const int bblk = b * (T_DIM / 128) + si;
    f32x4 acc[4][4] = {};

    for (int ks = 0; ks < NKB; ++ks) {
        if (ks) __syncthreads();
        if (w < 2) stage_half(Qh + tile_off(ablk, ks), &Ah[0][0][0], lane, w);
        else       stage_half(Xh + tile_off(bblk, ks), &Bh[0][0][0], lane, w - 2);
        __syncthreads();

        f16x8 ah[4], bh[4];
#pragma unroll
        for (int i2 = 0; i2 < 4; ++i2)
            ah[i2] = *(const f16x8*)&Ah[lg][t_off + i2 * 16 + l15][0];
#pragma unroll
        for (int j = 0; j < 4; ++j)
            bh[j] = *(const f16x8*)&Bh[lg][s_off + j * 16 + l15][0];
#pragma unroll
        for (int i2 = 0; i2 < 4; ++i2)
#pragma unroll
            for (int j = 0; j < 4; ++j)
                acc[i2][j] = __builtin_amdgcn_mfma_f32_16x16x32_f16(ah[i2], bh[j], acc[i2][j], 0, 0, 0);
    }

    float* base = attn + (size_t)b * T_DIM * T_DIM;
#pragma unroll
    for (int i2 = 0; i2 < 4; ++i2)
#pragma unroll
        for (int j = 0; j < 4; ++j)
#pragma unroll
            for (int rr = 0; rr < 4; ++rr) {
                int t = t0 + t_off + i2 * 16 + lg * 4 + rr;
                int s = s0 + s_off + j * 16 + l15;
                base[(size_t)t * T_DIM + s] = acc[i2][j][rr];
            }
}

// ---------- Kernel 5: in-place masked softmax, ONLINE max+sum (single read pass) ----------
__global__ __launch_bounds__(256) void k_softmax(float* __restrict__ attn) {
    const int row = blockIdx.x;
    const int t = row & (T_DIM - 1);
    float* p = attn + (size_t)row * T_DIM;
    const int tid = threadIdx.x;
    const int n = (t >= 2) ? t : 0;
    __shared__ float redm[4], redl[4];

    if (n == 0) {
        const float4 z = {0.f, 0.f, 0.f, 0.f};
        for (int s = tid * 4; s < T_DIM; s += 1024) *(float4*)&p[s] = z;
        return;
    }

    // online (m, l) over this thread's strided chunks, float4 reads
    float m = -1e30f, l = 0.f;
    for (int s = tid * 4; s < n; s += 1024) {
        float v[4];
        int cnt;
        if (s + 3 < n) {
            float4 q = *(const float4*)&p[s];
            v[0] = q.x; v[1] = q.y; v[2] = q.z; v[3] = q.w; cnt = 4;
        } else {
            cnt = n - s;
            for (int j = 0; j < cnt; ++j) v[j] = p[s + j];
        }
        float vm = v[0];
        for (int j = 1; j < cnt; ++j) vm = fmaxf(vm, v[j]);
        if (vm > m) { l *= expf(m - vm); m = vm; }
        for (int j = 0; j < cnt; ++j) l += expf(v[j] - m);
    }
    // wave-level merge of (m, l)
#pragma unroll
    for (int off = 32; off >= 1; off >>= 1) {
        float mo = __shfl_xor(m, off);
        float lo = __shfl_xor(l, off);
        float M = fmaxf(m, mo);
        l = l * expf(m - M) + lo * expf(mo - M);
        m = M;
    }
    if ((tid & 63) == 0) { redm[tid >> 6] = m; redl[tid >> 6] = l; }
    __syncthreads();
    {
        float M = fmaxf(fmaxf(redm[0], redm[1]), fmaxf(redm[2], redm[3]));
        float L = redl[0] * expf(redm[0] - M) + redl[1] * expf(redm[1] - M)
                + redl[2] * expf(redm[2] - M) + redl[3] * expf(redm[3] - M);
        m = M;
        l = L;
    }
    const float inv = 1.f / l;

    // write pass: probs for s < n, zeros elsewhere
    for (int s = tid * 4; s < T_DIM; s += 1024) {
        float4 o = {0.f, 0.f, 0.f, 0.f};
        if (s + 3 < n) {
            float4 v = *(float4*)&p[s];
            o.x = expf(v.x - m) * inv;
            o.y = expf(v.y - m) * inv;
            o.z = expf(v.z - m) * inv;
            o.w = expf(v.w - m) * inv;
        } else if (s < n) {
            float tmp[4] = {0.f, 0.f, 0.f, 0.f};
            for (int j = 0; j < 4; ++j)
                if (s + j < n) tmp[j] = expf(p[s + j] - m) * inv;
            o.x = tmp[0]; o.y = tmp[1]; o.z = tmp[2]; o.w = tmp[3];
        }
        *(float4*)&p[s] = o;
    }
}

extern "C" void kernel_launch(void* const* d_in, const int* in_sizes, int n_in,
                              void* d_out, int out_size, void* d_ws, size_t ws_size,
                              hipStream_t stream) {
    const float* inputs   = (const float*)d_in[0];   // [T,B,H]
    const float* rand_ctx = (const float*)d_in[1];   // [T,B,H]
    const float* W        = (const float*)d_in[2];   // [H,H]
    float* out  = (float*)d_out;
    float* attn = out + (size_t)T_DIM * B_DIM * 2 * H_DIM;

    unsigned short* Xh  = (unsigned short*)d_ws;
    unsigned short* Qh  = Xh + (size_t)33554432;
    unsigned short* Wth = Xh + (size_t)67108864;

    k_prep<<<dim3(T_DIM * B_DIM * 64 / 256), dim3(256), 0, stream>>>(
        inputs, rand_ctx, out, Xh);

    k_split_w<<<dim3(128), dim3(256), 0, stream>>>(W, Wth);

    k_qgemm_mfma<<<dim3(1024), dim3(256), 0, stream>>>(Xh, Wth, Qh);

    k_scores_mfma<<<dim3(2176), dim3(256), 0, stream>>>(Qh, Xh, attn);

    k_softmax<<<dim3(B_DIM * T_DIM), dim3(256), 0, stream>>>(attn);
}

// Round 10
// 302.205 us; speedup vs baseline: 2.6264x; 1.0118x over previous
//
#include <hip/hip_runtime.h>
#include <math.h>

#define T_DIM 2048
#define B_DIM 16
#define H_DIM 512
#define NKB   (H_DIM / 32)   // 16 k-blocks of 32
// out: results [T,B,2H] (33,554,432 f32) then attn [B,T,T] (67,108,864 f32)
// ws (ushort = fp16 bits), arrays TILED: tile(rowblk,kblk) = 8KB as [g(4)][row(128)][8]
// — byte-identical to the LDS image, staging is a linear coalesced copy.
//   Xh @0 (32MB), Qh @32Mi elems (32MB), Wth @64Mi elems (512KB).

typedef _Float16 f16x8 __attribute__((ext_vector_type(8)));
typedef float f32x4 __attribute__((ext_vector_type(4)));

__device__ __forceinline__ unsigned short h_bits(_Float16 h) {
    unsigned short u; __builtin_memcpy(&u, &h, 2); return u;
}

__device__ __forceinline__ size_t tile_off(int rowblk, int kblk) {
    return ((size_t)rowblk * NKB + kblk) * 4096;   // 4096 ushorts = 8KB per tile
}
__device__ __forceinline__ size_t tiled_idx(int r, int c) {
    return tile_off(r >> 7, c >> 5) + (size_t)((c >> 3) & 3) * 1024 + (size_t)(r & 127) * 8 + (c & 7);
}

// ---------- Kernel 1: results copy + X -> fp16 (tiled, batch-major) ----------
__global__ __launch_bounds__(256) void k_prep(const float* __restrict__ X,
                                              const float* __restrict__ RC,
                                              float* __restrict__ out,
                                              unsigned short* __restrict__ Xh) {
    int i = blockIdx.x * 256 + threadIdx.x;
    int row = i >> 6;                 // t*B + b
    int h0 = (i & 63) * 8;
    int t = row >> 4;
    int b = row & 15;
    const float* xp = X + (size_t)row * H_DIM + h0;
    float4 v0 = *(const float4*)xp;
    float4 v1 = *(const float4*)(xp + 4);
    float* op = out + (size_t)row * (2 * H_DIM) + h0;
    *(float4*)op = v0;
    *(float4*)(op + 4) = v1;
    const float* cp = RC + (size_t)row * H_DIM + h0;
    float4 c0 = *(const float4*)cp;
    float4 c1 = *(const float4*)(cp + 4);
    if (t < 2) { c0 = v0; c1 = v1; }
    *(float4*)(op + H_DIM) = c0;
    *(float4*)(op + H_DIM + 4) = c1;
    float xs[8] = {v0.x, v0.y, v0.z, v0.w, v1.x, v1.y, v1.z, v1.w};
    unsigned int hw[4];
#pragma unroll
    for (int e = 0; e < 4; ++e) {
        _Float16 a = (_Float16)xs[2 * e], bb = (_Float16)xs[2 * e + 1];
        hw[e] = (unsigned int)h_bits(a) | ((unsigned int)h_bits(bb) << 16);
    }
    int r = b * T_DIM + t;            // batch-major row index
    *(uint4*)(Xh + tiled_idx(r, h0)) = make_uint4(hw[0], hw[1], hw[2], hw[3]);
}

// ---------- Kernel 2: W -> transposed fp16, tiled [n][k] ----------
__global__ __launch_bounds__(256) void k_split_w(const float* __restrict__ W,
                                                 unsigned short* __restrict__ Wth) {
    int i = blockIdx.x * 256 + threadIdx.x;
    int n = i & 511;
    int k0 = (i >> 9) * 8;
    unsigned int hw[4];
#pragma unroll
    for (int e = 0; e < 4; ++e) {
        _Float16 h0 = (_Float16)W[(size_t)(k0 + 2 * e) * H_DIM + n];
        _Float16 h1 = (_Float16)W[(size_t)(k0 + 2 * e + 1) * H_DIM + n];
        hw[e] = (unsigned int)h_bits(h0) | ((unsigned int)h_bits(h1) << 16);
    }
    *(uint4*)(Wth + tiled_idx(n, k0)) = make_uint4(hw[0], hw[1], hw[2], hw[3]);
}

// ---------- staging: half of a pre-tiled 8KB tile -> LDS, linear coalesced copy ----------
__device__ __forceinline__ void stage_half(const unsigned short* __restrict__ src_tile,
                                           unsigned short* lds_base, int lane, int h) {
#pragma unroll
    for (int c = 0; c < 4; ++c) {
        const int ch = h * 4 + c;
        __builtin_amdgcn_global_load_lds(
            (const __attribute__((address_space(1))) void*)(src_tile + ch * 512 + lane * 8),
            (__attribute__((address_space(3))) void*)(lds_base + ch * 512),
            16, 0, 0);
    }
}

// ---------- Kernel 3: Q = X @ W, single-pass fp16 MFMA, BK=64 (2 kblks/phase) ----------
__global__ __launch_bounds__(256) void k_qgemm_mfma(const unsigned short* __restrict__ Xh,
                                                    const unsigned short* __restrict__ Wth,
                                                    unsigned short* __restrict__ Qh) {
    __shared__ __align__(16) unsigned short Ah[2][4][128][8], Bh[2][4][128][8];
    const int bid = blockIdx.x;                       // 1024 = 8 * 128
    const int swz = (bid & 7) * 128 + (bid >> 3);     // bijective
    const int mblk = swz >> 2, nblk = swz & 3;
    const int m0 = mblk * 128, n0 = nblk * 128;
    const int tid = threadIdx.x, lane = tid & 63, w = tid >> 6;
    const int t_off = (w >> 1) * 64, s_off = (w & 1) * 64;
    const int l15 = lane & 15, lg = lane >> 4;
    f32x4 acc[4][4] = {};

    for (int ksp = 0; ksp < NKB / 2; ++ksp) {
        if (ksp) __syncthreads();
        if (w < 2) {
            stage_half(Xh + tile_off(mblk, 2 * ksp),     &Ah[0][0][0][0], lane, w);
            stage_half(Xh + tile_off(mblk, 2 * ksp + 1), &Ah[1][0][0][0], lane, w);
        } else {
            stage_half(Wth + tile_off(nblk, 2 * ksp),     &Bh[0][0][0][0], lane, w - 2);
            stage_half(Wth + tile_off(nblk, 2 * ksp + 1), &Bh[1][0][0][0], lane, w - 2);
        }
        __syncthreads();

#pragma unroll
        for (int kk = 0; kk < 2; ++kk) {
            f16x8 ah[4], bh[4];
#pragma unroll
            for (int i2 = 0; i2 < 4; ++i2)
                ah[i2] = *(const f16x8*)&Ah[kk][lg][t_off + i2 * 16 + l15][0];
#pragma unroll
            for (int j = 0; j < 4; ++j)
                bh[j] = *(const f16x8*)&Bh[kk][lg][s_off + j * 16 + l15][0];
#pragma unroll
            for (int i2 = 0; i2 < 4; ++i2)
#pragma unroll
                for (int j = 0; j < 4; ++j)
                    acc[i2][j] = __builtin_amdgcn_mfma_f32_16x16x32_f16(ah[i2], bh[j], acc[i2][j], 0, 0, 0);
        }
    }

    // scatter epilogue (proven pattern), hi-only fp16 output
#pragma unroll
    for (int i2 = 0; i2 < 4; ++i2)
#pragma unroll
        for (int j = 0; j < 4; ++j)
#pragma unroll
            for (int r = 0; r < 4; ++r) {
                int R = m0 + t_off + i2 * 16 + lg * 4 + r;
                int C = n0 + s_off + j * 16 + l15;
                _Float16 qh = (_Float16)acc[i2][j][r];
                Qh[tiled_idx(R, C)] = h_bits(qh);
            }
}

// ---------- Kernel 4: scores, single-pass fp16 MFMA, BK=64, triangle + XCD swizzle ----------
__global__ __launch_bounds__(256) void k_scores_mfma(const unsigned short* __restrict__ Qh,
                                                     const unsigned short* __restrict__ Xh,
                                                     float* __restrict__ attn) {
    // 2176 live blocks = 16 batches x 136 triangle tile-pairs; 2176 = 8 * 272
    const int bid = blockIdx.x;
    const int swz = (bid & 7) * 272 + (bid >> 3);     // bijective XCD chunking
    const int b = swz / 136;
    const int r = swz - b * 136;
    int ti = (int)((sqrtf(8.f * (float)r + 1.f) - 1.f) * 0.5f);
    while ((ti + 1) * (ti + 2) / 2 <= r) ++ti;
    while (ti * (ti + 1) / 2 > r) --ti;
    const int si = r - ti * (ti + 1) / 2;             // si <= ti
    const int t0 = ti * 128, s0 = si * 128;

    __shared__ __align__(16) unsigned short Ah[2][4][128][8], Bh[2][4][128][8];
    const int tid = threadIdx.x, lane = tid & 63, w = tid >> 6;
    const int t_off = (w >> 1) * 64, s_off = (w & 1) * 64;
    const int l15 = lane & 15, lg = lane >> 4;
    const int ablk = b * (T_DIM / 128) + ti;
    const int bblk = b * (T_DIM / 128) + si;
    f32x4 acc[4][4] = {};

    for (int ksp = 0; ksp < NKB / 2; ++ksp) {
        if (ksp) __syncthreads();
        if (w < 2) {
            stage_half(Qh + tile_off(ablk, 2 * ksp),     &Ah[0][0][0][0], lane, w);
            stage_half(Qh + tile_off(ablk, 2 * ksp + 1), &Ah[1][0][0][0], lane, w);
        } else {
            stage_half(Xh + tile_off(bblk, 2 * ksp),     &Bh[0][0][0][0], lane, w - 2);
            stage_half(Xh + tile_off(bblk, 2 * ksp + 1), &Bh[1][0][0][0], lane, w - 2);
        }
        __syncthreads();

#pragma unroll
        for (int kk = 0; kk < 2; ++kk) {
            f16x8 ah[4], bh[4];
#pragma unroll
            for (int i2 = 0; i2 < 4; ++i2)
                ah[i2] = *(const f16x8*)&Ah[kk][lg][t_off + i2 * 16 + l15][0];
#pragma unroll
            for (int j = 0; j < 4; ++j)
                bh[j] = *(const f16x8*)&Bh[kk][lg][s_off + j * 16 + l15][0];
#pragma unroll
            for (int i2 = 0; i2 < 4; ++i2)
#pragma unroll
                for (int j = 0; j < 4; ++j)
                    acc[i2][j] = __builtin_amdgcn_mfma_f32_16x16x32_f16(ah[i2], bh[j], acc[i2][j], 0, 0, 0);
        }
    }

    float* base = attn + (size_t)b * T_DIM * T_DIM;
#pragma unroll
    for (int i2 = 0; i2 < 4; ++i2)
#pragma unroll
        for (int j = 0; j < 4; ++j)
#pragma unroll
            for (int rr = 0; rr < 4; ++rr) {
                int t = t0 + t_off + i2 * 16 + lg * 4 + rr;
                int s = s0 + s_off + j * 16 + l15;
                base[(size_t)t * T_DIM + s] = acc[i2][j][rr];
            }
}

// ---------- Kernel 5: in-place masked softmax, ONLINE max+sum (single read pass) ----------
__global__ __launch_bounds__(256) void k_softmax(float* __restrict__ attn) {
    const int row = blockIdx.x;
    const int t = row & (T_DIM - 1);
    float* p = attn + (size_t)row * T_DIM;
    const int tid = threadIdx.x;
    const int n = (t >= 2) ? t : 0;
    __shared__ float redm[4], redl[4];

    if (n == 0) {
        const float4 z = {0.f, 0.f, 0.f, 0.f};
        for (int s = tid * 4; s < T_DIM; s += 1024) *(float4*)&p[s] = z;
        return;
    }

    // online (m, l) over this thread's strided chunks, float4 reads
    float m = -1e30f, l = 0.f;
    for (int s = tid * 4; s < n; s += 1024) {
        float v[4];
        int cnt;
        if (s + 3 < n) {
            float4 q = *(const float4*)&p[s];
            v[0] = q.x; v[1] = q.y; v[2] = q.z; v[3] = q.w; cnt = 4;
        } else {
            cnt = n - s;
            for (int j = 0; j < cnt; ++j) v[j] = p[s + j];
        }
        float vm = v[0];
        for (int j = 1; j < cnt; ++j) vm = fmaxf(vm, v[j]);
        if (vm > m) { l *= expf(m - vm); m = vm; }
        for (int j = 0; j < cnt; ++j) l += expf(v[j] - m);
    }
    // wave-level merge of (m, l)
#pragma unroll
    for (int off = 32; off >= 1; off >>= 1) {
        float mo = __shfl_xor(m, off);
        float lo = __shfl_xor(l, off);
        float M = fmaxf(m, mo);
        l = l * expf(m - M) + lo * expf(mo - M);
        m = M;
    }
    if ((tid & 63) == 0) { redm[tid >> 6] = m; redl[tid >> 6] = l; }
    __syncthreads();
    {
        float M = fmaxf(fmaxf(redm[0], redm[1]), fmaxf(redm[2], redm[3]));
        float L = redl[0] * expf(redm[0] - M) + redl[1] * expf(redm[1] - M)
                + redl[2] * expf(redm[2] - M) + redl[3] * expf(redm[3] - M);
        m = M;
        l = L;
    }
    const float inv = 1.f / l;

    // write pass: probs for s < n, zeros elsewhere
    for (int s = tid * 4; s < T_DIM; s += 1024) {
        float4 o = {0.f, 0.f, 0.f, 0.f};
        if (s + 3 < n) {
            float4 v = *(float4*)&p[s];
            o.x = expf(v.x - m) * inv;
            o.y = expf(v.y - m) * inv;
            o.z = expf(v.z - m) * inv;
            o.w = expf(v.w - m) * inv;
        } else if (s < n) {
            float tmp[4] = {0.f, 0.f, 0.f, 0.f};
            for (int j = 0; j < 4; ++j)
                if (s + j < n) tmp[j] = expf(p[s + j] - m) * inv;
            o.x = tmp[0]; o.y = tmp[1]; o.z = tmp[2]; o.w = tmp[3];
        }
        *(float4*)&p[s] = o;
    }
}

extern "C" void kernel_launch(void* const* d_in, const int* in_sizes, int n_in,
                              void* d_out, int out_size, void* d_ws, size_t ws_size,
                              hipStream_t stream) {
    const float* inputs   = (const float*)d_in[0];   // [T,B,H]
    const float* rand_ctx = (const float*)d_in[1];   // [T,B,H]
    const float* W        = (const float*)d_in[2];   // [H,H]
    float* out  = (float*)d_out;
    float* attn = out + (size_t)T_DIM * B_DIM * 2 * H_DIM;

    unsigned short* Xh  = (unsigned short*)d_ws;
    unsigned short* Qh  = Xh + (size_t)33554432;
    unsigned short* Wth = Xh + (size_t)67108864;

    k_prep<<<dim3(T_DIM * B_DIM * 64 / 256), dim3(256), 0, stream>>>(
        inputs, rand_ctx, out, Xh);

    k_split_w<<<dim3(128), dim3(256), 0, stream>>>(W, Wth);

    k_qgemm_mfma<<<dim3(1024), dim3(256), 0, stream>>>(Xh, Wth, Qh);

    k_scores_mfma<<<dim3(2176), dim3(256), 0, stream>>>(Qh, Xh, attn);

    k_softmax<<<dim3(B_DIM * T_DIM), dim3(256), 0, stream>>>(attn);
}